// Round 4
// baseline (688.949 us; speedup 1.0000x reference)
//
#include <hip/hip_runtime.h>

// VQ nearest-code search + gather + loss, MFMA split-bf16 edition.
// z_real [32,1024,512] f32, z_imag same, embedding [4096,512] f32.
// N=32768 rows, D=512, K=4096.
// Outputs (flat f32): quantized (16777216) | z_imag (16777216) | loss (1).
//
// Distance argmin: s_k = 0.5||e_k||^2 - x.e_k. The dot is computed with
// 3-pass split-bf16 MFMA (hi*hi + hi*lo + lo*hi), error ~4e-5 vs typical
// min-gap ~8. Scratch for the bf16 splits lives INSIDE d_out (region is
// consumed by the gemm, then overwritten by the gather epilogue).
//
// Round-4 revision: round-3 counters showed 49% MfmaUtil with ~1830 cyc
// of exposed stage+drain per step (vmcnt(0) drain ~ HBM latency at every
// barrier; the 2 resident blocks drain in lockstep so they don't cover
// each other). Fix = amortize, not overlap: BK 32->64 doubles MFMA per
// barrier pair (192/wave = 3724 cyc/CU) against the same ~1500cyc drain.
//  * LDS set 96 KB -> 1 block/CU; __launch_bounds__(256,1) so the
//    compiler has the full 512-reg budget (acc=128 AGPR + frags).
//  * Same proven 2-barrier-per-step schedule (round-1 rewrite was -20%).
//  * Swizzle generalized to 8 chunks/row: stored chunk = logical ^ (row&7);
//    write side pre-swizzles the global column ((lane&7)^(lane>>3))<<3 on
//    the linear global_load_lds dest; read side XORs ((ks*4+q)^(c&7))<<3.

#define NROWS 32768
#define DDIM  512
#define KCODES 4096
#define BM 128
#define BN 256
#define BK 64
#define KSPLIT 4
#define KPER (KCODES / KSPLIT)   // 1024 codes per k-split block

typedef short s16x8 __attribute__((ext_vector_type(8)));
typedef float f32x4 __attribute__((ext_vector_type(4)));
typedef unsigned long long u64;
typedef unsigned short u16;
typedef unsigned int u32;

__device__ __forceinline__ void glds16(const void* g, void* l) {
    __builtin_amdgcn_global_load_lds(
        (const __attribute__((address_space(1))) void*)g,
        (__attribute__((address_space(3))) void*)l, 16, 0, 0);
}

// float -> bf16 bits (RNE) + the value it rounds back to. Even if rounding
// differs slightly from HW, lo = bf16(x - hi) compensates (self-correcting).
__device__ __forceinline__ u16 f2bf(float x, float& back) {
    u32 b = __float_as_uint(x);
    u32 r = (b + 0x7fffu + ((b >> 16) & 1u)) >> 16;
    back = __uint_as_float(r << 16);
    return (u16)r;
}

// ------------------- K0: split fp32 -> bf16 hi/lo pair ----------------------
__global__ __launch_bounds__(256) void split_kernel(
    const float* __restrict__ src, u16* __restrict__ hi, u16* __restrict__ lo) {
    const size_t i = ((size_t)blockIdx.x * 256 + threadIdx.x) * 4;
    float4 v = *(const float4*)(src + i);
    ushort4 hv, lv;
    float bx, by, bz, bw;
    hv.x = f2bf(v.x, bx); hv.y = f2bf(v.y, by);
    hv.z = f2bf(v.z, bz); hv.w = f2bf(v.w, bw);
    float d;
    lv.x = f2bf(v.x - bx, d); lv.y = f2bf(v.y - by, d);
    lv.z = f2bf(v.z - bz, d); lv.w = f2bf(v.w - bw, d);
    *(ushort4*)(hi + i) = hv;
    *(ushort4*)(lo + i) = lv;
}

// ------------------------- K1: h[k] = 0.5*||e_k||^2 -------------------------
__global__ void enorm_kernel(const float* __restrict__ E, float* __restrict__ h) {
    const int k = blockIdx.x * 4 + (threadIdx.x >> 6);
    const int lane = threadIdx.x & 63;
    const float* row = E + (size_t)k * DDIM;
    float s = 0.f;
    #pragma unroll
    for (int d = 0; d < DDIM / 64; ++d) {
        float v = row[lane + d * 64];
        s += v * v;
    }
    #pragma unroll
    for (int off = 32; off; off >>= 1) s += __shfl_down(s, off, 64);
    if (lane == 0) h[k] = 0.5f * s;
}

// ------------- K2: MFMA score GEMM + fused running argmin -------------------
// grid = 256 row-blocks x 4 k-splits. Block: 256 thr = 4 waves (2x2),
// wave computes 64x128 of the 128x256 score tile via 4x8 16x16x32 MFMAs,
// 3 MFMA passes (hh, hl, lh) per fragment pair, 2 K-slices per d-step.
// 2-barrier-per-step schedule; 4 k-tiles x 8 d-steps = 32 steps.
__global__ __launch_bounds__(256, 1) void gemm_argmin_kernel(
    const u16* __restrict__ Xhi, const u16* __restrict__ Xlo,
    const u16* __restrict__ Ehi, const u16* __restrict__ Elo,
    const float* __restrict__ h, u64* __restrict__ packed) {
    // Contiguous: Ahi[128][64] | Alo[128][64] | Bhi[256][64] | Blo[256][64]
    // = 96 KB. Unit u (of 96) = 8 rows = 1 KB at smem + u*512 (u16).
    __shared__ __align__(16) u16 smem[49152];
    __shared__ u64 red[BM][2];

    const int t = threadIdx.x;
    const int lane = t & 63;
    const int wid = t >> 6;
    const int wr = wid >> 1, wc = wid & 1;
    const int bx = blockIdx.x & 255;
    const int ks_ = blockIdx.x >> 8;
    const size_t rowBase = (size_t)bx * BM;
    const int kBase = ks_ * KPER;

    const int lrow = lane >> 3;          // row within an 8-row unit
    // Write side of the swizzle: linear dest = 16B chunk (lane&7) of row
    // (lane>>3); it must hold logical chunk (lane&7)^(row&7).
    const int chcol = (((lane & 7) ^ (lane >> 3)) << 3);  // bf16-elem offset

    // Per-wave staging pointer table: units u = wid*24 + r, r in [0,24).
    // u<16: Ahi<-Xhi rows u*8 ; u<32: Alo<-Xlo rows (u-16)*8 ;
    // u<64: Bhi<-Ehi rows (u-32)*8 ; else Blo<-Elo rows (u-64)*8.
    // p[r] includes the unit's row offset — stage address is p[r] + d0 ONLY.
    const u16* p[24];
    #pragma unroll
    for (int r = 0; r < 24; ++r) {
        const int u = wid * 24 + r;
        const u16* src = (u < 16) ? Xhi : (u < 32) ? Xlo : (u < 64) ? Ehi : Elo;
        const size_t grow = (u < 32) ? (rowBase + (size_t)(u & 15) * 8)
                                     : ((size_t)kBase + (size_t)((u - 32) & 31) * 8);
        p[r] = src + (grow + lrow) * DDIM + chcol;
    }
    u16* const sbase = smem + wid * (24 * 512);  // wave-uniform LDS dest base

    const int c = lane & 15, q = lane >> 4;

    float best[16];
    u32 besti[16];
    #pragma unroll
    for (int i = 0; i < 16; ++i) { best[i] = 3.4e38f; besti[i] = 0; }

    for (int kt2 = 0; kt2 < KPER / BN; ++kt2) {       // 4 k-tiles of 256
        f32x4 acc[4][8];
        #pragma unroll
        for (int i = 0; i < 4; ++i)
            #pragma unroll
            for (int j = 0; j < 8; ++j) acc[i][j] = f32x4{0.f, 0.f, 0.f, 0.f};

        for (int d0 = 0; d0 < DDIM; d0 += BK) {
            __syncthreads();   // previous step's LDS reads done
            #pragma unroll
            for (int r = 0; r < 24; ++r)
                glds16(p[r] + d0, sbase + r * 512);
            __syncthreads();   // all buffers staged (vmcnt(0) implied)

            #pragma unroll
            for (int ks = 0; ks < 2; ++ks) {
                // read side: logical chunk cq=ks*4+q of row m at stored
                // chunk cq ^ (m&7); m&7 == c&7 for all fragment rows.
                const int qoff = (((ks * 4 + q) ^ (c & 7)) << 3);
                s16x8 ah[4], al[4];
                #pragma unroll
                for (int i = 0; i < 4; ++i) {
                    const int m = wr * 64 + i * 16 + c;
                    ah[i] = *(const s16x8*)(smem + m * BK + qoff);
                    al[i] = *(const s16x8*)(smem + 8192 + m * BK + qoff);
                }
                #pragma unroll
                for (int j = 0; j < 8; ++j) {
                    const int n = wc * 128 + j * 16 + c;
                    const s16x8 bh = *(const s16x8*)(smem + 16384 + n * BK + qoff);
                    const s16x8 bl = *(const s16x8*)(smem + 32768 + n * BK + qoff);
                    #pragma unroll
                    for (int i = 0; i < 4; ++i) {
                        acc[i][j] = __builtin_amdgcn_mfma_f32_16x16x32_bf16(ah[i], bh, acc[i][j], 0, 0, 0);
                        acc[i][j] = __builtin_amdgcn_mfma_f32_16x16x32_bf16(ah[i], bl, acc[i][j], 0, 0, 0);
                        acc[i][j] = __builtin_amdgcn_mfma_f32_16x16x32_bf16(al[i], bh, acc[i][j], 0, 0, 0);
                    }
                }
            }
        }
        // fold h, update running argmin. cols ascend (kt2, then j) => strict
        // '<' keeps lowest index per lane; cross-lane ties in packed min.
        #pragma unroll
        for (int j = 0; j < 8; ++j) {
            const int col = kBase + kt2 * BN + wc * 128 + j * 16 + c;
            const float hv = h[col];
            #pragma unroll
            for (int i = 0; i < 4; ++i)
                #pragma unroll
                for (int r = 0; r < 4; ++r) {
                    const float s = hv - acc[i][j][r];
                    const int slot = i * 4 + r;
                    if (s < best[slot]) { best[slot] = s; besti[slot] = (u32)col; }
                }
        }
        // advance B-side (E) staging pointers to the next 256-code tile
        #pragma unroll
        for (int r = 0; r < 24; ++r)
            if (wid * 24 + r >= 32) p[r] += (size_t)BN * DDIM;
    }

    // pack (score,idx); min over the 16 lanes of each quad (same rows)
    u64 p64[16];
    #pragma unroll
    for (int i = 0; i < 16; ++i) {
        u32 ub = __float_as_uint(best[i]);
        ub = (ub & 0x80000000u) ? ~ub : (ub | 0x80000000u);
        p64[i] = ((u64)ub << 32) | (u64)besti[i];
    }
    #pragma unroll
    for (int m = 1; m < 16; m <<= 1)
        #pragma unroll
        for (int i = 0; i < 16; ++i) {
            u64 o = __shfl_xor(p64[i], m, 64);
            if (o < p64[i]) p64[i] = o;
        }
    if (c == 0) {
        #pragma unroll
        for (int i = 0; i < 16; ++i) {
            const int row = wr * 64 + (i >> 2) * 16 + q * 4 + (i & 3);
            red[row][wc] = p64[i];
        }
    }
    __syncthreads();
    if (t < BM) {
        u64 a = red[t][0], b = red[t][1];
        packed[(rowBase + t) * KSPLIT + ks_] = a < b ? a : b;
    }
}

// ----------------- K3: merge 4 k-split results -> final idx -----------------
__global__ void merge_kernel(const u64* __restrict__ packed, int* __restrict__ idx) {
    const int n = blockIdx.x * 256 + threadIdx.x;
    u64 m = packed[(size_t)n * 4];
    #pragma unroll
    for (int s = 1; s < 4; ++s) {
        u64 v = packed[(size_t)n * 4 + s];
        if (v < m) m = v;
    }
    idx[n] = (int)(u32)m;
}

// ---------- K4: gather quantized, copy z_imag, per-block loss partial -------
__global__ __launch_bounds__(256) void gather_kernel(
    const float* __restrict__ Zr, const float* __restrict__ Zi,
    const float* __restrict__ E, const int* __restrict__ idx,
    float* __restrict__ out, float* __restrict__ partials) {
    const int i = blockIdx.x * 256 + threadIdx.x;   // float4 index
    const size_t base = (size_t)i * 4;
    const int n = i >> 7;                 // 128 float4 per row
    const int d = (i & 127) << 2;
    const int k = idx[n];

    float4 qv = *(const float4*)(E + (size_t)k * DDIM + d);
    float4 z  = *(const float4*)(Zr + base);
    float4 zi = *(const float4*)(Zi + base);
    *(float4*)(out + base) = qv;
    *(float4*)(out + (size_t)NROWS * DDIM + base) = zi;

    const float dx = qv.x - z.x, dy = qv.y - z.y, dz = qv.z - z.z, dw = qv.w - z.w;
    float s = dx * dx + dy * dy + dz * dz + dw * dw;

    #pragma unroll
    for (int off = 32; off; off >>= 1) s += __shfl_down(s, off, 64);
    __shared__ float wred[4];
    const int lane = threadIdx.x & 63, wv = threadIdx.x >> 6;
    if (lane == 0) wred[wv] = s;
    __syncthreads();
    if (threadIdx.x == 0)
        partials[blockIdx.x] = wred[0] + wred[1] + wred[2] + wred[3];
}

// --------------------- K5: deterministic loss reduction ---------------------
__global__ void finalize_kernel(const float* __restrict__ partials,
                                float* __restrict__ out_loss) {
    __shared__ double red[256];
    double s = 0.0;
    for (int i = threadIdx.x; i < 16384; i += 256) s += (double)partials[i];
    red[threadIdx.x] = s;
    __syncthreads();
    for (int off = 128; off; off >>= 1) {
        if (threadIdx.x < off) red[threadIdx.x] += red[threadIdx.x + off];
        __syncthreads();
    }
    if (threadIdx.x == 0)
        *out_loss = (float)(1.25 * red[0] / 16777216.0);
}

extern "C" void kernel_launch(void* const* d_in, const int* in_sizes, int n_in,
                              void* d_out, int out_size, void* d_ws, size_t ws_size,
                              hipStream_t stream) {
    const float* z_real = (const float*)d_in[0];
    const float* z_imag = (const float*)d_in[1];
    const float* emb    = (const float*)d_in[2];
    float* out = (float*)d_out;
    char* outc = (char*)d_out;

    // Scratch INSIDE d_out (consumed before the gather overwrites it):
    //   region1 (quantized, 64 MB): Xhi 32 MB | Xlo 32 MB
    //   region2 (z_imag, 64 MB):    Ehi 4 MB | Elo 4 MB | h 16 KB | packed 1 MB
    u16* Xhi = (u16*)outc;
    u16* Xlo = (u16*)(outc + 33554432);
    char* reg2 = outc + 67108864;
    u16* Ehi = (u16*)reg2;
    u16* Elo = (u16*)(reg2 + 4194304);
    float* h = (float*)(reg2 + 8388608);
    u64* packed = (u64*)(reg2 + 8388608 + 16384);
    // ws: idx 128 KB | partials 64 KB  (196 KB total)
    int*   idx      = (int*)d_ws;
    float* partials = (float*)((char*)d_ws + 131072);

    split_kernel<<<16384, 256, 0, stream>>>(z_real, Xhi, Xlo);
    split_kernel<<<2048, 256, 0, stream>>>(emb, Ehi, Elo);
    enorm_kernel<<<KCODES / 4, 256, 0, stream>>>(emb, h);
    gemm_argmin_kernel<<<256 * KSPLIT, 256, 0, stream>>>(Xhi, Xlo, Ehi, Elo, h, packed);
    merge_kernel<<<NROWS / 256, 256, 0, stream>>>(packed, idx);
    gather_kernel<<<(NROWS * DDIM / 4) / 256, 256, 0, stream>>>(
        z_real, z_imag, emb, idx, out, partials);
    finalize_kernel<<<1, 256, 0, stream>>>(partials, out + (size_t)2 * NROWS * DDIM);
}

// Round 5
// 658.006 us; speedup vs baseline: 1.0470x; 1.0470x over previous
//
#include <hip/hip_runtime.h>

// VQ nearest-code search + gather + loss, MFMA split-bf16 edition.
// z_real [32,1024,512] f32, z_imag same, embedding [4096,512] f32.
// N=32768 rows, D=512, K=4096.
// Outputs (flat f32): quantized (16777216) | z_imag (16777216) | loss (1).
//
// Distance argmin: s_k = 0.5||e_k||^2 - x.e_k. The dot is computed with
// 3-pass split-bf16 MFMA (hi*hi + hi*lo + lo*hi), error ~4e-5 vs typical
// min-gap ~8. Scratch for the bf16 splits lives INSIDE d_out (region is
// consumed by the gemm, then overwritten by the gather epilogue).
//
// Round-5 revision: round-4 (BK=64, 1 block/CU) regressed -> reverted to
// the verified round-3 structure (BK=32, BN=256, 48 KB LDS, 2 blocks/CU,
// 2-barrier schedule, 394 us). New: T1 XCD-aware bijective block swizzle.
// Default round-robin spreads all 4 k-splits over every XCD -> E working
// set 8 MB > 4 MB L2, so B-side staging (16/24 units) runs at HBM latency.
// Swizzle swz=(bid&7)*128+(bid>>3), ks=swz>>8, bx=swz&255 gives each XCD
// 128 contiguous-bx blocks of ONE k-split: E-slab 2 MB = L2-resident, and
// a block's 256 KB X-slab stays L2-hot across its 4 kt2 re-reads.

#define NROWS 32768
#define DDIM  512
#define KCODES 4096
#define BM 128
#define BN 256
#define BK 32
#define KSPLIT 4
#define KPER (KCODES / KSPLIT)   // 1024 codes per k-split block

typedef short s16x8 __attribute__((ext_vector_type(8)));
typedef float f32x4 __attribute__((ext_vector_type(4)));
typedef unsigned long long u64;
typedef unsigned short u16;
typedef unsigned int u32;

__device__ __forceinline__ void glds16(const void* g, void* l) {
    __builtin_amdgcn_global_load_lds(
        (const __attribute__((address_space(1))) void*)g,
        (__attribute__((address_space(3))) void*)l, 16, 0, 0);
}

// float -> bf16 bits (RNE) + the value it rounds back to. Even if rounding
// differs slightly from HW, lo = bf16(x - hi) compensates (self-correcting).
__device__ __forceinline__ u16 f2bf(float x, float& back) {
    u32 b = __float_as_uint(x);
    u32 r = (b + 0x7fffu + ((b >> 16) & 1u)) >> 16;
    back = __uint_as_float(r << 16);
    return (u16)r;
}

// ------------------- K0: split fp32 -> bf16 hi/lo pair ----------------------
__global__ __launch_bounds__(256) void split_kernel(
    const float* __restrict__ src, u16* __restrict__ hi, u16* __restrict__ lo) {
    const size_t i = ((size_t)blockIdx.x * 256 + threadIdx.x) * 4;
    float4 v = *(const float4*)(src + i);
    ushort4 hv, lv;
    float bx, by, bz, bw;
    hv.x = f2bf(v.x, bx); hv.y = f2bf(v.y, by);
    hv.z = f2bf(v.z, bz); hv.w = f2bf(v.w, bw);
    float d;
    lv.x = f2bf(v.x - bx, d); lv.y = f2bf(v.y - by, d);
    lv.z = f2bf(v.z - bz, d); lv.w = f2bf(v.w - bw, d);
    *(ushort4*)(hi + i) = hv;
    *(ushort4*)(lo + i) = lv;
}

// ------------------------- K1: h[k] = 0.5*||e_k||^2 -------------------------
__global__ void enorm_kernel(const float* __restrict__ E, float* __restrict__ h) {
    const int k = blockIdx.x * 4 + (threadIdx.x >> 6);
    const int lane = threadIdx.x & 63;
    const float* row = E + (size_t)k * DDIM;
    float s = 0.f;
    #pragma unroll
    for (int d = 0; d < DDIM / 64; ++d) {
        float v = row[lane + d * 64];
        s += v * v;
    }
    #pragma unroll
    for (int off = 32; off; off >>= 1) s += __shfl_down(s, off, 64);
    if (lane == 0) h[k] = 0.5f * s;
}

// ------------- K2: MFMA score GEMM + fused running argmin -------------------
// grid = 256 row-blocks x 4 k-splits (XCD-swizzled). Block: 256 thr = 4
// waves (2x2), wave computes 64x128 of the 128x256 score tile via 4x8
// 16x16x32 MFMAs, 3 MFMA passes (hh, hl, lh) per fragment pair.
// Proven 2-barrier-per-step schedule; 4 k-tiles x 16 d-steps = 64 steps.
__global__ __launch_bounds__(256, 2) void gemm_argmin_kernel(
    const u16* __restrict__ Xhi, const u16* __restrict__ Xlo,
    const u16* __restrict__ Ehi, const u16* __restrict__ Elo,
    const float* __restrict__ h, u64* __restrict__ packed) {
    // Contiguous buffers: Ahi[128][32] | Alo[128][32] | Bhi[256][32] | Blo[256][32]
    // = 48 KB. Unit u (of 48) = 16 rows = 512 u16 at smem + u*512.
    __shared__ __align__(16) u16 smem[24576];
    __shared__ u64 red[BM][2];

    const int t = threadIdx.x;
    const int lane = t & 63;
    const int wid = t >> 6;
    const int wr = wid >> 1, wc = wid & 1;
    // T1 XCD-aware bijective swizzle: grid 1024 = 8 XCDs x 128. Each XCD
    // gets 128 contiguous-bx blocks of a single k-split (XCD pair per ks).
    const int bid = blockIdx.x;
    const int swz = ((bid & 7) << 7) | (bid >> 3);
    const int bx = swz & 255;
    const int ks_ = swz >> 8;
    const size_t rowBase = (size_t)bx * BM;
    const int kBase = ks_ * KPER;

    const int lrow = lane >> 2;          // row within a 16-row unit
    // XOR-swizzle (both-sides, HW-verified conflict-free in round 1):
    // linear dest slot (lane&3) of row r holds logical chunk
    // (lane&3)^((r>>1)&3); (r>>1)&3 == (lane>>3)&3 for this mapping.
    const int chunk = (((lane & 3) ^ ((lane >> 3) & 3)) << 3);  // bf16-elem off

    // Per-wave staging pointer table: units u = wid*12 + r, r in [0,12).
    // u<8: Ahi<-Xhi rows u*16 ; u<16: Alo<-Xlo rows (u-8)*16 ;
    // u<32: Bhi<-Ehi rows (u-16)*16 ; else Blo<-Elo rows (u-32)*16.
    // p[r] includes the unit's row offset — stage address is p[r] + d0 ONLY.
    const u16* p[12];
    #pragma unroll
    for (int r = 0; r < 12; ++r) {
        const int u = wid * 12 + r;
        const u16* src = (u < 8) ? Xhi : (u < 16) ? Xlo : (u < 32) ? Ehi : Elo;
        const size_t grow = (u < 16) ? (rowBase + (size_t)(u & 7) * 16)
                                     : ((size_t)kBase + (size_t)((u - 16) & 15) * 16);
        p[r] = src + (grow + lrow) * DDIM + chunk;
    }
    u16* const sbase = smem + wid * (12 * 512);  // wave-uniform LDS dest base

    const int c = lane & 15, q = lane >> 4;
    // read side: logical chunk q of row m lives at slot q ^ ((m>>1)&3);
    // (m>>1)&3 == (c>>1)&3 for all fragment rows used below.
    const int qoff = ((q ^ ((c >> 1) & 3)) << 3);

    float best[16];
    u32 besti[16];
    #pragma unroll
    for (int i = 0; i < 16; ++i) { best[i] = 3.4e38f; besti[i] = 0; }

    for (int kt2 = 0; kt2 < KPER / BN; ++kt2) {       // 4 k-tiles of 256
        f32x4 acc[4][8];
        #pragma unroll
        for (int i = 0; i < 4; ++i)
            #pragma unroll
            for (int j = 0; j < 8; ++j) acc[i][j] = f32x4{0.f, 0.f, 0.f, 0.f};

        for (int d0 = 0; d0 < DDIM; d0 += BK) {
            __syncthreads();   // previous step's LDS reads done
            #pragma unroll
            for (int r = 0; r < 12; ++r)
                glds16(p[r] + d0, sbase + r * 512);
            __syncthreads();   // all buffers staged (vmcnt(0) implied)

            s16x8 ah[4], al[4];
            #pragma unroll
            for (int i = 0; i < 4; ++i) {
                const int m = wr * 64 + i * 16 + c;
                ah[i] = *(const s16x8*)(smem + m * BK + qoff);
                al[i] = *(const s16x8*)(smem + 4096 + m * BK + qoff);
            }
            #pragma unroll
            for (int j = 0; j < 8; ++j) {
                const int n = wc * 128 + j * 16 + c;
                const s16x8 bh = *(const s16x8*)(smem + 8192 + n * BK + qoff);
                const s16x8 bl = *(const s16x8*)(smem + 16384 + n * BK + qoff);
                #pragma unroll
                for (int i = 0; i < 4; ++i) {
                    acc[i][j] = __builtin_amdgcn_mfma_f32_16x16x32_bf16(ah[i], bh, acc[i][j], 0, 0, 0);
                    acc[i][j] = __builtin_amdgcn_mfma_f32_16x16x32_bf16(ah[i], bl, acc[i][j], 0, 0, 0);
                    acc[i][j] = __builtin_amdgcn_mfma_f32_16x16x32_bf16(al[i], bh, acc[i][j], 0, 0, 0);
                }
            }
        }
        // fold h, update running argmin. cols ascend (kt2, then j) => strict
        // '<' keeps lowest index per lane; cross-lane ties in packed min.
        #pragma unroll
        for (int j = 0; j < 8; ++j) {
            const int col = kBase + kt2 * BN + wc * 128 + j * 16 + c;
            const float hv = h[col];
            #pragma unroll
            for (int i = 0; i < 4; ++i)
                #pragma unroll
                for (int r = 0; r < 4; ++r) {
                    const float s = hv - acc[i][j][r];
                    const int slot = i * 4 + r;
                    if (s < best[slot]) { best[slot] = s; besti[slot] = (u32)col; }
                }
        }
        // advance B-side (E) staging pointers to the next 256-code tile
        #pragma unroll
        for (int r = 0; r < 12; ++r)
            if (wid * 12 + r >= 16) p[r] += (size_t)BN * DDIM;
    }

    // pack (score,idx); min over the 16 lanes of each quad (same rows)
    u64 p64[16];
    #pragma unroll
    for (int i = 0; i < 16; ++i) {
        u32 ub = __float_as_uint(best[i]);
        ub = (ub & 0x80000000u) ? ~ub : (ub | 0x80000000u);
        p64[i] = ((u64)ub << 32) | (u64)besti[i];
    }
    #pragma unroll
    for (int m = 1; m < 16; m <<= 1)
        #pragma unroll
        for (int i = 0; i < 16; ++i) {
            u64 o = __shfl_xor(p64[i], m, 64);
            if (o < p64[i]) p64[i] = o;
        }
    if (c == 0) {
        #pragma unroll
        for (int i = 0; i < 16; ++i) {
            const int row = wr * 64 + (i >> 2) * 16 + q * 4 + (i & 3);
            red[row][wc] = p64[i];
        }
    }
    __syncthreads();
    if (t < BM) {
        u64 a = red[t][0], b = red[t][1];
        packed[(rowBase + t) * KSPLIT + ks_] = a < b ? a : b;
    }
}

// ----------------- K3: merge 4 k-split results -> final idx -----------------
__global__ void merge_kernel(const u64* __restrict__ packed, int* __restrict__ idx) {
    const int n = blockIdx.x * 256 + threadIdx.x;
    u64 m = packed[(size_t)n * 4];
    #pragma unroll
    for (int s = 1; s < 4; ++s) {
        u64 v = packed[(size_t)n * 4 + s];
        if (v < m) m = v;
    }
    idx[n] = (int)(u32)m;
}

// ---------- K4: gather quantized, copy z_imag, per-block loss partial -------
__global__ __launch_bounds__(256) void gather_kernel(
    const float* __restrict__ Zr, const float* __restrict__ Zi,
    const float* __restrict__ E, const int* __restrict__ idx,
    float* __restrict__ out, float* __restrict__ partials) {
    const int i = blockIdx.x * 256 + threadIdx.x;   // float4 index
    const size_t base = (size_t)i * 4;
    const int n = i >> 7;                 // 128 float4 per row
    const int d = (i & 127) << 2;
    const int k = idx[n];

    float4 qv = *(const float4*)(E + (size_t)k * DDIM + d);
    float4 z  = *(const float4*)(Zr + base);
    float4 zi = *(const float4*)(Zi + base);
    *(float4*)(out + base) = qv;
    *(float4*)(out + (size_t)NROWS * DDIM + base) = zi;

    const float dx = qv.x - z.x, dy = qv.y - z.y, dz = qv.z - z.z, dw = qv.w - z.w;
    float s = dx * dx + dy * dy + dz * dz + dw * dw;

    #pragma unroll
    for (int off = 32; off; off >>= 1) s += __shfl_down(s, off, 64);
    __shared__ float wred[4];
    const int lane = threadIdx.x & 63, wv = threadIdx.x >> 6;
    if (lane == 0) wred[wv] = s;
    __syncthreads();
    if (threadIdx.x == 0)
        partials[blockIdx.x] = wred[0] + wred[1] + wred[2] + wred[3];
}

// --------------------- K5: deterministic loss reduction ---------------------
__global__ void finalize_kernel(const float* __restrict__ partials,
                                float* __restrict__ out_loss) {
    __shared__ double red[256];
    double s = 0.0;
    for (int i = threadIdx.x; i < 16384; i += 256) s += (double)partials[i];
    red[threadIdx.x] = s;
    __syncthreads();
    for (int off = 128; off; off >>= 1) {
        if (threadIdx.x < off) red[threadIdx.x] += red[threadIdx.x + off];
        __syncthreads();
    }
    if (threadIdx.x == 0)
        *out_loss = (float)(1.25 * red[0] / 16777216.0);
}

extern "C" void kernel_launch(void* const* d_in, const int* in_sizes, int n_in,
                              void* d_out, int out_size, void* d_ws, size_t ws_size,
                              hipStream_t stream) {
    const float* z_real = (const float*)d_in[0];
    const float* z_imag = (const float*)d_in[1];
    const float* emb    = (const float*)d_in[2];
    float* out = (float*)d_out;
    char* outc = (char*)d_out;

    // Scratch INSIDE d_out (consumed before the gather overwrites it):
    //   region1 (quantized, 64 MB): Xhi 32 MB | Xlo 32 MB
    //   region2 (z_imag, 64 MB):    Ehi 4 MB | Elo 4 MB | h 16 KB | packed 1 MB
    u16* Xhi = (u16*)outc;
    u16* Xlo = (u16*)(outc + 33554432);
    char* reg2 = outc + 67108864;
    u16* Ehi = (u16*)reg2;
    u16* Elo = (u16*)(reg2 + 4194304);
    float* h = (float*)(reg2 + 8388608);
    u64* packed = (u64*)(reg2 + 8388608 + 16384);
    // ws: idx 128 KB | partials 64 KB  (196 KB total)
    int*   idx      = (int*)d_ws;
    float* partials = (float*)((char*)d_ws + 131072);

    split_kernel<<<16384, 256, 0, stream>>>(z_real, Xhi, Xlo);
    split_kernel<<<2048, 256, 0, stream>>>(emb, Ehi, Elo);
    enorm_kernel<<<KCODES / 4, 256, 0, stream>>>(emb, h);
    gemm_argmin_kernel<<<256 * KSPLIT, 256, 0, stream>>>(Xhi, Xlo, Ehi, Elo, h, packed);
    merge_kernel<<<NROWS / 256, 256, 0, stream>>>(packed, idx);
    gather_kernel<<<(NROWS * DDIM / 4) / 256, 256, 0, stream>>>(
        z_real, z_imag, emb, idx, out, partials);
    finalize_kernel<<<1, 256, 0, stream>>>(partials, out + (size_t)2 * NROWS * DDIM);
}